// Round 14
// baseline (316.954 us; speedup 1.0000x reference)
//
#include <hip/hip_runtime.h>
#include <math.h>

#define N_NODES 10000
#define N_EDGES 160000
#define N_GRAPH 512

#define NEG_INF (-1e30f)

typedef __attribute__((ext_vector_type(8))) short s16x8;
typedef __attribute__((ext_vector_type(4))) float f32x4;

__device__ __forceinline__ unsigned short f2b(float f) {
  union { float f; unsigned u; } c{f};
  unsigned u = c.u;
  return (unsigned short)((u + 0x7fff + ((u >> 16) & 1)) >> 16);
}
__device__ __forceinline__ float b2f(unsigned short h) {
  union { unsigned u; float f; } c{(unsigned)h << 16};
  return c.f;
}
__device__ __forceinline__ void up2(unsigned d, float& lo, float& hi) {
  union { unsigned u; float f; } a{d << 16}, b{d & 0xffff0000u};
  lo = a.f; hi = b.f;
}
__device__ __forceinline__ float lrelu(float x) { return x > 0.f ? x : 0.2f * x; }

#define GLL16(gp, lp)                                                          \
  __builtin_amdgcn_global_load_lds(                                            \
      (const __attribute__((address_space(1))) unsigned int*)(gp),             \
      (__attribute__((address_space(3))) unsigned int*)(lp), 16, 0, 0)

// ======================= CSR build =======================
__global__ void k_count(const int* __restrict__ dst, const int* __restrict__ batch,
                        int* __restrict__ deg, int* __restrict__ gcnt) {
  int i = blockIdx.x * 256 + threadIdx.x;
  if (i < N_EDGES) atomicAdd(&deg[dst[i]], 1);
  if (i < N_NODES) atomicAdd(&gcnt[batch[i]], 1);
}

// two exclusive scans in one launch (single block)
__global__ void k_scan2(const int* __restrict__ in1, int* __restrict__ out1, int n1,
                        const int* __restrict__ in2, int* __restrict__ out2, int n2) {
  __shared__ int buf[1024];
  __shared__ int carry_s;
#pragma unroll 1
  for (int pass = 0; pass < 2; ++pass) {
    const int* in = pass ? in2 : in1;
    int* out = pass ? out2 : out1;
    const int n = pass ? n2 : n1;
    if (threadIdx.x == 0) carry_s = 0;
    __syncthreads();
    for (int base = 0; base < n; base += 1024) {
      int i = base + (int)threadIdx.x;
      int v = (i < n) ? in[i] : 0;
      buf[threadIdx.x] = v;
      __syncthreads();
      for (int off = 1; off < 1024; off <<= 1) {
        int t = (threadIdx.x >= (unsigned)off) ? buf[threadIdx.x - off] : 0;
        __syncthreads();
        buf[threadIdx.x] += t;
        __syncthreads();
      }
      int carry = carry_s;
      if (i < n) out[i] = carry + buf[threadIdx.x] - v;
      __syncthreads();
      if (threadIdx.x == 0) carry_s = carry + buf[1023];
      __syncthreads();
    }
    if (threadIdx.x == 0) out[n] = carry_s;
    __syncthreads();
  }
}

__global__ void k_fill(const int* __restrict__ src, const int* __restrict__ dst,
                       const int* __restrict__ rowoff, int* __restrict__ cursor,
                       int* __restrict__ csr) {
  int e = blockIdx.x * 256 + threadIdx.x;
  if (e < N_EDGES) {
    int d = dst[e];
    int p = atomicAdd(&cursor[d], 1);
    csr[rowoff[d] + p] = src[e];
  }
}

__global__ __launch_bounds__(256) void k_sortseg(const int* __restrict__ rowoff,
                                                 int* __restrict__ vals) {
  const int node = blockIdx.x * 4 + (threadIdx.x >> 6);
  if (node >= N_NODES) return;
  const int lane = threadIdx.x & 63;
  const int a = rowoff[node], b = rowoff[node + 1];
  const int deg = b - a;
  if (deg <= 1) return;
  if (deg <= 64) {
    int v = (lane < deg) ? vals[a + lane] : 0x7fffffff;
#pragma unroll
    for (int ph = 0; ph < 64; ++ph) {
      const int par = ph & 1;
      const bool left = ((lane & 1) == par);
      const int partner = left ? lane + 1 : lane - 1;
      const int pv = __shfl(v, partner & 63);
      if (partner >= 0 && partner < 64) v = left ? min(v, pv) : max(v, pv);
    }
    if (lane < deg) vals[a + lane] = v;
  } else if (lane == 0) {
    for (int p = a + 1; p < b; ++p) {
      int v = vals[p];
      int q = p - 1;
      while (q >= a && vals[q] > v) { vals[q + 1] = vals[q]; --q; }
      vals[q + 1] = v;
    }
  }
}

// ======================= conversions =======================
__global__ __launch_bounds__(256) void k_convT(const float* __restrict__ in,
                                               unsigned short* __restrict__ out,
                                               int K, int M) {
  __shared__ float t[32][33];
  const int mb = blockIdx.x * 32, kb = blockIdx.y * 32;
  const int tx = threadIdx.x & 31, ty = threadIdx.x >> 5;
#pragma unroll
  for (int r = ty; r < 32; r += 8) t[r][tx] = in[(size_t)(kb + r) * M + mb + tx];
  __syncthreads();
#pragma unroll
  for (int r = ty; r < 32; r += 8)
    out[(size_t)(mb + r) * K + kb + tx] = f2b(t[tx][r]);
}

// wS[f][h] = sum_c W[f, h*256+c] * att[h*256+c]   (layer-1 rank-1 mix)
__global__ void k_wmix(const float* __restrict__ W, const float* __restrict__ attS,
                       const float* __restrict__ attD, float* __restrict__ wS,
                       float* __restrict__ wD) {
  const int i = blockIdx.x * 256 + threadIdx.x;
  if (i >= 512) return;
  const int f = i >> 2, h = i & 3;
  const float* wrow = W + (size_t)f * 1024 + h * 256;
  const float* as = attS + h * 256;
  const float* ad = attD + h * 256;
  float s = 0.f, d = 0.f;
  for (int c = 0; c < 256; ++c) {
    const float w = wrow[c];
    s += w * as[c];
    d += w * ad[c];
  }
  wS[f * 4 + h] = s;
  wD[f * 4 + h] = d;
}

// fused: x -> x_bf (bf16) AND aS/aD = x @ wS/wD. 4 nodes/block, wave per node.
__global__ __launch_bounds__(256) void k_prep_x(const float* __restrict__ x,
                                                const float* __restrict__ wS,
                                                const float* __restrict__ wD,
                                                unsigned short* __restrict__ x_bf,
                                                float* __restrict__ aS,
                                                float* __restrict__ aD) {
  __shared__ float sS[128][4], sD[128][4];
  const int tid = threadIdx.x;
  for (int i = tid; i < 512; i += 256) {
    sS[i >> 2][i & 3] = wS[i];
    sD[i >> 2][i & 3] = wD[i];
  }
  __syncthreads();
  const int node = blockIdx.x * 4 + (tid >> 6);
  if (node >= N_NODES) return;
  const int lane = tid & 63;
  const float2 xv = ((const float2*)(x + (size_t)node * 128))[lane];
  const unsigned o = (unsigned)f2b(xv.x) | ((unsigned)f2b(xv.y) << 16);
  ((unsigned*)x_bf)[(size_t)node * 64 + lane] = o;
  const float4 s0 = *(const float4*)sS[lane * 2];
  const float4 s1 = *(const float4*)sS[lane * 2 + 1];
  const float4 d0 = *(const float4*)sD[lane * 2];
  const float4 d1 = *(const float4*)sD[lane * 2 + 1];
  float a0 = xv.x * s0.x + xv.y * s1.x;
  float a1 = xv.x * s0.y + xv.y * s1.y;
  float a2 = xv.x * s0.z + xv.y * s1.z;
  float a3 = xv.x * s0.w + xv.y * s1.w;
  float b0 = xv.x * d0.x + xv.y * d1.x;
  float b1 = xv.x * d0.y + xv.y * d1.y;
  float b2 = xv.x * d0.z + xv.y * d1.z;
  float b3 = xv.x * d0.w + xv.y * d1.w;
#pragma unroll
  for (int off = 32; off; off >>= 1) {
    a0 += __shfl_xor(a0, off); a1 += __shfl_xor(a1, off);
    a2 += __shfl_xor(a2, off); a3 += __shfl_xor(a3, off);
    b0 += __shfl_xor(b0, off); b1 += __shfl_xor(b1, off);
    b2 += __shfl_xor(b2, off); b3 += __shfl_xor(b3, off);
  }
  if (lane == 0) {
    *(float4*)&aS[(size_t)node * 4] = make_float4(a0, a1, a2, a3);
    *(float4*)&aD[(size_t)node * 4] = make_float4(b0, b1, b2, b3);
  }
}

// x-space aggregation for layer 1 (working set 2.5MB, L2-fit; softmax fused)
__global__ __launch_bounds__(256) void k_aggx(
    const unsigned short* __restrict__ x_bf, const float* __restrict__ aS,
    const float* __restrict__ aD, const int* __restrict__ rowoff,
    const int* __restrict__ csr, unsigned short* __restrict__ xt) {
  const int wv = threadIdx.x >> 6;
  const int lane = threadIdx.x & 63;
  const int node = blockIdx.x * 4 + wv;
  if (node >= N_NODES) return;

  __shared__ int s_src_all[4][64];
  __shared__ float s_alp_all[4][64][4];
  int* s_src = s_src_all[wv];
  float (*s_alp)[4] = s_alp_all[wv];

  const int r0 = rowoff[node];
  const int deg = rowoff[node + 1] - r0;
  const float4 ad4 = *(const float4*)&aD[(size_t)node * 4];

  float acc[8];
#pragma unroll
  for (int j = 0; j < 8; ++j) acc[j] = 0.f;

  auto gather = [&](int cnt) {
    int e = 0;
    for (; e + 4 <= cnt; e += 4) {
      unsigned v[4];
      float4 al[4];
#pragma unroll
      for (int u = 0; u < 4; ++u) {
        const int s = s_src[e + u];
        al[u] = *(const float4*)s_alp[e + u];
        v[u] = ((const unsigned*)(x_bf + ((size_t)s << 7)))[lane];
      }
#pragma unroll
      for (int u = 0; u < 4; ++u) {
        float lo, hi;
        up2(v[u], lo, hi);
        acc[0] += al[u].x * lo; acc[1] += al[u].x * hi;
        acc[2] += al[u].y * lo; acc[3] += al[u].y * hi;
        acc[4] += al[u].z * lo; acc[5] += al[u].z * hi;
        acc[6] += al[u].w * lo; acc[7] += al[u].w * hi;
      }
    }
    for (; e < cnt; ++e) {
      const int s = s_src[e];
      const float4 al = *(const float4*)s_alp[e];
      const unsigned v = ((const unsigned*)(x_bf + ((size_t)s << 7)))[lane];
      float lo, hi;
      up2(v, lo, hi);
      acc[0] += al.x * lo; acc[1] += al.x * hi;
      acc[2] += al.y * lo; acc[3] += al.y * hi;
      acc[4] += al.z * lo; acc[5] += al.z * hi;
      acc[6] += al.w * lo; acc[7] += al.w * hi;
    }
  };

  if (deg <= 64) {
    float l0, l1, l2, l3;
    int sE = 0;
    const bool act = lane < deg;
    if (act) {
      sE = csr[r0 + lane];
      const float4 sv = *(const float4*)&aS[(size_t)sE * 4];
      l0 = lrelu(sv.x + ad4.x);
      l1 = lrelu(sv.y + ad4.y);
      l2 = lrelu(sv.z + ad4.z);
      l3 = lrelu(sv.w + ad4.w);
    } else {
      l0 = l1 = l2 = l3 = NEG_INF;
    }
    float m0 = l0, m1 = l1, m2 = l2, m3 = l3;
#pragma unroll
    for (int off = 32; off; off >>= 1) {
      m0 = fmaxf(m0, __shfl_xor(m0, off));
      m1 = fmaxf(m1, __shfl_xor(m1, off));
      m2 = fmaxf(m2, __shfl_xor(m2, off));
      m3 = fmaxf(m3, __shfl_xor(m3, off));
    }
    float e0 = act ? __expf(l0 - m0) : 0.f;
    float e1 = act ? __expf(l1 - m1) : 0.f;
    float e2 = act ? __expf(l2 - m2) : 0.f;
    float e3 = act ? __expf(l3 - m3) : 0.f;
    float s0 = e0, s1 = e1, s2 = e2, s3 = e3;
#pragma unroll
    for (int off = 32; off; off >>= 1) {
      s0 += __shfl_xor(s0, off);
      s1 += __shfl_xor(s1, off);
      s2 += __shfl_xor(s2, off);
      s3 += __shfl_xor(s3, off);
    }
    if (act) {
      s_src[lane] = sE;
      s_alp[lane][0] = e0 / (s0 + 1e-16f);
      s_alp[lane][1] = e1 / (s1 + 1e-16f);
      s_alp[lane][2] = e2 / (s2 + 1e-16f);
      s_alp[lane][3] = e3 / (s3 + 1e-16f);
    }
    gather(deg);
  } else {
    auto logits = [&](int idx, float& a, float& b, float& c, float& d, int& s) {
      s = csr[r0 + idx];
      const float4 sv = *(const float4*)&aS[(size_t)s * 4];
      a = lrelu(sv.x + ad4.x);
      b = lrelu(sv.y + ad4.y);
      c = lrelu(sv.z + ad4.z);
      d = lrelu(sv.w + ad4.w);
    };
    float m0 = NEG_INF, m1 = NEG_INF, m2 = NEG_INF, m3 = NEG_INF;
    for (int base = 0; base < deg; base += 64) {
      if (base + lane < deg) {
        float a, b, c, d; int s;
        logits(base + lane, a, b, c, d, s);
        m0 = fmaxf(m0, a); m1 = fmaxf(m1, b); m2 = fmaxf(m2, c); m3 = fmaxf(m3, d);
      }
    }
#pragma unroll
    for (int off = 32; off; off >>= 1) {
      m0 = fmaxf(m0, __shfl_xor(m0, off));
      m1 = fmaxf(m1, __shfl_xor(m1, off));
      m2 = fmaxf(m2, __shfl_xor(m2, off));
      m3 = fmaxf(m3, __shfl_xor(m3, off));
    }
    float s0 = 0.f, s1 = 0.f, s2 = 0.f, s3 = 0.f;
    for (int base = 0; base < deg; base += 64) {
      if (base + lane < deg) {
        float a, b, c, d; int s;
        logits(base + lane, a, b, c, d, s);
        s0 += __expf(a - m0); s1 += __expf(b - m1);
        s2 += __expf(c - m2); s3 += __expf(d - m3);
      }
    }
#pragma unroll
    for (int off = 32; off; off >>= 1) {
      s0 += __shfl_xor(s0, off);
      s1 += __shfl_xor(s1, off);
      s2 += __shfl_xor(s2, off);
      s3 += __shfl_xor(s3, off);
    }
    const float d0 = 1.f / (s0 + 1e-16f), d1 = 1.f / (s1 + 1e-16f);
    const float d2 = 1.f / (s2 + 1e-16f), d3 = 1.f / (s3 + 1e-16f);
    for (int base = 0; base < deg; base += 64) {
      const int cnt = min(64, deg - base);
      if (lane < cnt) {
        float a, b, c, d; int s;
        logits(base + lane, a, b, c, d, s);
        s_src[lane] = s;
        s_alp[lane][0] = __expf(a - m0) * d0;
        s_alp[lane][1] = __expf(b - m1) * d1;
        s_alp[lane][2] = __expf(c - m2) * d2;
        s_alp[lane][3] = __expf(d - m3) * d3;
      }
      gather(cnt);
    }
  }

#pragma unroll
  for (int h = 0; h < 4; ++h) {
    const unsigned o = (unsigned)f2b(acc[h * 2]) | ((unsigned)f2b(acc[h * 2 + 1]) << 16);
    ((unsigned*)xt)[(size_t)node * 256 + h * 64 + lane] = o;
  }
}

// ======================= bf16 MFMA GEMM (strided, XCD-swizzled, BK=64) ============
// K must be a multiple of 64.
__global__ __launch_bounds__(256) void k_gemm_bf16(
    const unsigned short* __restrict__ A, int lda,
    const unsigned short* __restrict__ Bt, int ldb,
    unsigned short* __restrict__ Cbf, int ldc,
    int M, int N, int K, int nbx) {
  __shared__ unsigned short As[128 * 64];
  __shared__ unsigned short Bs[128 * 64];
  const int tid = threadIdx.x;
  const int lane = tid & 63, wave = tid >> 6;
  const int wr = wave >> 1, wc = wave & 1;

  // XCD-aware swizzle over the linear block id (nwg % 8 == 0 by caller pad)
  const int nwg = nbx * gridDim.y;
  int bid = blockIdx.y * nbx + blockIdx.x;
  {
    const int per = nwg >> 3;
    const int xcd = bid & 7, idx = bid >> 3;
    bid = xcd * per + idx;
  }
  const int by = bid / nbx, bx = bid % nbx;
  const int m0 = by * 128, n0 = bx * 128;

  f32x4 acc[4][4];
#pragma unroll
  for (int i = 0; i < 4; ++i)
#pragma unroll
    for (int j = 0; j < 4; ++j) acc[i][j] = (f32x4){0.f, 0.f, 0.f, 0.f};

  // staging: lane covers row (lane>>3), col (lane&7)*8 within a 8x64 panel;
  // wave stages 4 panels (32 rows) per matrix per K-tile.
  const int l8 = lane >> 3;
  const int kp8 = (lane & 7) * 8;
  int rA[4], rB[4];
#pragma unroll
  for (int s = 0; s < 4; ++s) {
    rA[s] = min(m0 + wave * 32 + s * 8 + l8, M - 1);
    rB[s] = n0 + wave * 32 + s * 8 + l8;
  }
  const unsigned short* pA[4];
  const unsigned short* pB[4];
#pragma unroll
  for (int s = 0; s < 4; ++s) {
    pA[s] = A + (size_t)rA[s] * lda + kp8;
    pB[s] = Bt + (size_t)rB[s] * ldb + kp8;
  }
  unsigned short* lA = As + wave * 2048;  // 32 rows * 64 cols
  unsigned short* lB = Bs + wave * 2048;

  const int fr = lane & 15, kg = (lane >> 4) * 8;

  for (int kb = 0; kb < K; kb += 64) {
#pragma unroll
    for (int s = 0; s < 4; ++s) GLL16(pA[s] + kb, lA + s * 512);
#pragma unroll
    for (int s = 0; s < 4; ++s) GLL16(pB[s] + kb, lB + s * 512);
    __syncthreads();

    s16x8 a[4][2], b[4][2];
#pragma unroll
    for (int m = 0; m < 4; ++m) {
      const unsigned short* base = &As[(wr * 64 + m * 16 + fr) * 64 + kg];
      a[m][0] = *(const s16x8*)base;
      a[m][1] = *(const s16x8*)(base + 32);
    }
#pragma unroll
    for (int n = 0; n < 4; ++n) {
      const unsigned short* base = &Bs[(wc * 64 + n * 16 + fr) * 64 + kg];
      b[n][0] = *(const s16x8*)base;
      b[n][1] = *(const s16x8*)(base + 32);
    }
#pragma unroll
    for (int m = 0; m < 4; ++m)
#pragma unroll
      for (int n = 0; n < 4; ++n) {
        acc[m][n] = __builtin_amdgcn_mfma_f32_16x16x32_bf16(a[m][0], b[n][0], acc[m][n], 0, 0, 0);
        acc[m][n] = __builtin_amdgcn_mfma_f32_16x16x32_bf16(a[m][1], b[n][1], acc[m][n], 0, 0, 0);
      }
    __syncthreads();
  }

  const int frow = (lane >> 4) * 4;
#pragma unroll
  for (int m = 0; m < 4; ++m) {
#pragma unroll
    for (int r = 0; r < 4; ++r) {
      const int row = m0 + wr * 64 + m * 16 + frow + r;
      if (row < M) {
#pragma unroll
        for (int n = 0; n < 4; ++n) {
          const int col = n0 + wc * 64 + n * 16 + fr;
          Cbf[(size_t)row * ldc + col] = f2b(acc[m][n][r]);
        }
      }
    }
  }
}

// ======================= layer-1 block-diagonal GEMM, fused epilogue =============
__global__ __launch_bounds__(256) void k_gemm_l1(
    const unsigned short* __restrict__ xt,    // [N][512]
    const unsigned short* __restrict__ W1t,   // [1024][128]
    unsigned short* __restrict__ Cbf,         // [N][1024]
    int M, const float* __restrict__ bias, const float* __restrict__ bn) {
  constexpr int K = 128, lda = 512, ldb = 128, ldc = 1024;
  __shared__ unsigned short As[128 * 32];
  __shared__ unsigned short Bs[128 * 32];
  const int tid = threadIdx.x;
  const int lane = tid & 63, wave = tid >> 6;
  const int wr = wave >> 1, wc = wave & 1;
  const int bx = blockIdx.x;
  const int h = bx >> 1;
  const int n0 = (bx & 1) * 128;
  const int colbase = h * 256;
  const int m0 = blockIdx.y * 128;
  const unsigned short* A = xt + h * 128;
  const unsigned short* Bt = W1t + (size_t)colbase * ldb;

  f32x4 acc[4][4];
#pragma unroll
  for (int i = 0; i < 4; ++i)
#pragma unroll
    for (int j = 0; j < 4; ++j) acc[i][j] = (f32x4){0.f, 0.f, 0.f, 0.f};

  const int l4 = lane >> 2;
  const int kp8 = (lane & 3) * 8;
  int rA0 = m0 + wave * 32 + l4;
  int rA1 = rA0 + 16;
  rA0 = min(rA0, M - 1);
  rA1 = min(rA1, M - 1);
  const int rB0 = n0 + wave * 32 + l4;
  const int rB1 = rB0 + 16;
  const unsigned short* pA0 = A + (size_t)rA0 * lda + kp8;
  const unsigned short* pA1 = A + (size_t)rA1 * lda + kp8;
  const unsigned short* pB0 = Bt + (size_t)rB0 * ldb + kp8;
  const unsigned short* pB1 = Bt + (size_t)rB1 * ldb + kp8;
  unsigned short* lA = As + wave * 1024;
  unsigned short* lB = Bs + wave * 1024;

  const int fr = lane & 15, kg = (lane >> 4) * 8;

  for (int kb = 0; kb < K; kb += 32) {
    GLL16(pA0 + kb, lA);
    GLL16(pA1 + kb, lA + 512);
    GLL16(pB0 + kb, lB);
    GLL16(pB1 + kb, lB + 512);
    __syncthreads();

    s16x8 a[4], b[4];
#pragma unroll
    for (int m = 0; m < 4; ++m)
      a[m] = *(const s16x8*)&As[(wr * 64 + m * 16 + fr) * 32 + kg];
#pragma unroll
    for (int n = 0; n < 4; ++n)
      b[n] = *(const s16x8*)&Bs[(wc * 64 + n * 16 + fr) * 32 + kg];
#pragma unroll
    for (int m = 0; m < 4; ++m)
#pragma unroll
      for (int n = 0; n < 4; ++n)
        acc[m][n] = __builtin_amdgcn_mfma_f32_16x16x32_bf16(a[m], b[n], acc[m][n], 0, 0, 0);
    __syncthreads();
  }

  const int frow = (lane >> 4) * 4;
#pragma unroll
  for (int m = 0; m < 4; ++m) {
#pragma unroll
    for (int r = 0; r < 4; ++r) {
      const int row = m0 + wr * 64 + m * 16 + frow + r;
      if (row < M) {
#pragma unroll
        for (int n = 0; n < 4; ++n) {
          const int col = n0 + wc * 64 + n * 16 + fr;
          const int gcol = colbase + col;
          float v = acc[m][n][r] + bias[gcol];
          const float g = bn[gcol], b = bn[1024 + gcol];
          const float mu = bn[2048 + gcol], var = bn[3072 + gcol];
          v = (v - mu) * (g * rsqrtf(var + 1e-5f)) + b;
          v = v > 0.f ? v : (__expf(v) - 1.f);
          Cbf[(size_t)row * ldc + gcol] = f2b(v);
        }
      }
    }
  }
}

// ======================= head MLP fp32 GEMM =======================
template <int K, int M>
__global__ __launch_bounds__(256) void k_head_fc(
    const float* __restrict__ A, const float* __restrict__ W,
    float* __restrict__ C, const float* __restrict__ bias,
    const float* __restrict__ bn) {
  constexpr int KQ = K / 4;
  __shared__ float Ap[8 * K];
  __shared__ float part[4][8][64];
  const int tid = threadIdx.x;
  const int g0 = blockIdx.y * 8;
  const int m0 = blockIdx.x * 64;
  const int c = tid & 63;
  const int q = tid >> 6;

  for (int i = tid; i < 8 * K / 4; i += 256)
    ((float4*)Ap)[i] = ((const float4*)(A + (size_t)g0 * K))[i];
  __syncthreads();

  float acc[8];
#pragma unroll
  for (int r = 0; r < 8; ++r) acc[r] = 0.f;

  const float* Wc = W + m0 + c;
  const int k0 = q * KQ;
  for (int k = k0; k < k0 + KQ; k += 4) {
    float wv[4];
#pragma unroll
    for (int u = 0; u < 4; ++u) wv[u] = Wc[(size_t)(k + u) * M];
#pragma unroll
    for (int r = 0; r < 8; ++r) {
      const float4 a4 = *(const float4*)&Ap[r * K + k];
      acc[r] += a4.x * wv[0] + a4.y * wv[1] + a4.z * wv[2] + a4.w * wv[3];
    }
  }

#pragma unroll
  for (int r = 0; r < 8; ++r) part[q][r][c] = acc[r];
  __syncthreads();

  for (int i = tid; i < 512; i += 256) {
    const int r = i >> 6, cc = i & 63;
    float v = part[0][r][cc] + part[1][r][cc] + part[2][r][cc] + part[3][r][cc];
    const int gc = m0 + cc;
    v += bias[gc];
    const float g = bn[gc], b = bn[M + gc], mu = bn[2 * M + gc], var = bn[3 * M + gc];
    v = (v - mu) * (g * rsqrtf(var + 1e-5f)) + b;
    v = fmaxf(v, 0.f);
    C[(size_t)(g0 + r) * M + gc] = v;
  }
}

// ======================= attention scores from h (layers 2,3) =====================
template <int HEADS>
__global__ __launch_bounds__(256) void k_att(const unsigned short* __restrict__ h,
                                             const float* __restrict__ att_s,
                                             const float* __restrict__ att_d,
                                             float* __restrict__ aS,
                                             float* __restrict__ aD) {
  const int pair = blockIdx.x * 4 + (threadIdx.x >> 6);
  if (pair >= N_NODES * HEADS) return;
  const int node = pair / HEADS, hd = pair % HEADS;
  const int lane = threadIdx.x & 63;
  const unsigned short* row = h + (size_t)node * HEADS * 256 + hd * 256;
  const ushort4 v = *(const ushort4*)&row[lane * 4];
  const float4 s4 = *(const float4*)&att_s[hd * 256 + lane * 4];
  const float4 d4 = *(const float4*)&att_d[hd * 256 + lane * 4];
  float ss = b2f(v.x) * s4.x + b2f(v.y) * s4.y + b2f(v.z) * s4.z + b2f(v.w) * s4.w;
  float sd = b2f(v.x) * d4.x + b2f(v.y) * d4.y + b2f(v.z) * d4.z + b2f(v.w) * d4.w;
#pragma unroll
  for (int off = 32; off; off >>= 1) {
    ss += __shfl_xor(ss, off);
    sd += __shfl_xor(sd, off);
  }
  if (lane == 0) {
    aS[pair] = ss;
    aD[pair] = sd;
  }
}

// ======================= half-row-wave GAT aggregation, H=4 (layer 2) =============
__global__ __launch_bounds__(256) void k_aggw4(
    const unsigned short* __restrict__ hpre, const float* __restrict__ aS,
    const float* __restrict__ aD, const int* __restrict__ rowoff,
    const int* __restrict__ csr, const float* __restrict__ bias,
    const float* __restrict__ bn, unsigned short* __restrict__ outb) {
  const int wv = threadIdx.x >> 6;
  const int lane = threadIdx.x & 63;
  const int node = blockIdx.x * 2 + (wv >> 1);
  const int half = wv & 1;
  if (node >= N_NODES) return;

  __shared__ int s_src_all[4][64];
  __shared__ float s_alp_all[4][64][2];
  int* s_src = s_src_all[wv];
  float (*s_alp)[2] = s_alp_all[wv];

  const int r0 = rowoff[node];
  const int deg = rowoff[node + 1] - r0;
  const float2 ad2 = *(const float2*)&aD[(size_t)node * 4 + half * 2];

  float acc[8];
#pragma unroll
  for (int j = 0; j < 8; ++j) acc[j] = 0.f;

  const int hg = lane >> 5;
  const size_t choff = (size_t)half * 512;

  auto gather = [&](int cnt) {
    int e = 0;
    for (; e + 4 <= cnt; e += 4) {
      uint4 v[4];
      float al[4];
#pragma unroll
      for (int u = 0; u < 4; ++u) {
        const int s = s_src[e + u];
        al[u] = s_alp[e + u][hg];
        v[u] = ((const uint4*)(hpre + ((size_t)s << 10) + choff))[lane];
      }
#pragma unroll
      for (int u = 0; u < 4; ++u) {
        float lo, hi;
        up2(v[u].x, lo, hi); acc[0] += al[u] * lo; acc[1] += al[u] * hi;
        up2(v[u].y, lo, hi); acc[2] += al[u] * lo; acc[3] += al[u] * hi;
        up2(v[u].z, lo, hi); acc[4] += al[u] * lo; acc[5] += al[u] * hi;
        up2(v[u].w, lo, hi); acc[6] += al[u] * lo; acc[7] += al[u] * hi;
      }
    }
    for (; e < cnt; ++e) {
      const int s = s_src[e];
      const float al = s_alp[e][hg];
      const uint4 v = ((const uint4*)(hpre + ((size_t)s << 10) + choff))[lane];
      float lo, hi;
      up2(v.x, lo, hi); acc[0] += al * lo; acc[1] += al * hi;
      up2(v.y, lo, hi); acc[2] += al * lo; acc[3] += al * hi;
      up2(v.z, lo, hi); acc[4] += al * lo; acc[5] += al * hi;
      up2(v.w, lo, hi); acc[6] += al * lo; acc[7] += al * hi;
    }
  };

  if (deg <= 64) {
    float la, lb;
    int sE = 0;
    const bool act = lane < deg;
    if (act) {
      sE = csr[r0 + lane];
      const float2 sv = *(const float2*)&aS[(size_t)sE * 4 + half * 2];
      la = lrelu(sv.x + ad2.x);
      lb = lrelu(sv.y + ad2.y);
    } else {
      la = lb = NEG_INF;
    }
    float ma = la, mb = lb;
#pragma unroll
    for (int off = 32; off; off >>= 1) {
      ma = fmaxf(ma, __shfl_xor(ma, off));
      mb = fmaxf(mb, __shfl_xor(mb, off));
    }
    float ea = act ? __expf(la - ma) : 0.f;
    float eb = act ? __expf(lb - mb) : 0.f;
    float sa = ea, sb = eb;
#pragma unroll
    for (int off = 32; off; off >>= 1) {
      sa += __shfl_xor(sa, off);
      sb += __shfl_xor(sb, off);
    }
    if (act) {
      s_src[lane] = sE;
      s_alp[lane][0] = ea / (sa + 1e-16f);
      s_alp[lane][1] = eb / (sb + 1e-16f);
    }
    gather(deg);
  } else {
    auto logits = [&](int idx, float& a, float& b, int& s) {
      s = csr[r0 + idx];
      const float2 sv = *(const float2*)&aS[(size_t)s * 4 + half * 2];
      a = lrelu(sv.x + ad2.x);
      b = lrelu(sv.y + ad2.y);
    };
    float ma = NEG_INF, mb = NEG_INF;
    for (int base = 0; base < deg; base += 64) {
      if (base + lane < deg) {
        float a, b; int s;
        logits(base + lane, a, b, s);
        ma = fmaxf(ma, a); mb = fmaxf(mb, b);
      }
    }
#pragma unroll
    for (int off = 32; off; off >>= 1) {
      ma = fmaxf(ma, __shfl_xor(ma, off));
      mb = fmaxf(mb, __shfl_xor(mb, off));
    }
    float sa = 0.f, sb = 0.f;
    for (int base = 0; base < deg; base += 64) {
      if (base + lane < deg) {
        float a, b; int s;
        logits(base + lane, a, b, s);
        sa += __expf(a - ma); sb += __expf(b - mb);
      }
    }
#pragma unroll
    for (int off = 32; off; off >>= 1) {
      sa += __shfl_xor(sa, off);
      sb += __shfl_xor(sb, off);
    }
    const float da = 1.f / (sa + 1e-16f), db = 1.f / (sb + 1e-16f);
    for (int base = 0; base < deg; base += 64) {
      const int cnt = min(64, deg - base);
      if (lane < cnt) {
        float a, b; int s;
        logits(base + lane, a, b, s);
        s_src[lane] = s;
        s_alp[lane][0] = __expf(a - ma) * da;
        s_alp[lane][1] = __expf(b - mb) * db;
      }
      gather(cnt);
    }
  }

  const int cb = half * 512 + lane * 8;
  unsigned od[4];
#pragma unroll
  for (int jj = 0; jj < 2; ++jj) {
    const float4 bi = *(const float4*)&bias[cb + jj * 4];
    const float4 gg = *(const float4*)&bn[cb + jj * 4];
    const float4 bb = *(const float4*)&bn[1024 + cb + jj * 4];
    const float4 mm = *(const float4*)&bn[2048 + cb + jj * 4];
    const float4 vv = *(const float4*)&bn[3072 + cb + jj * 4];
    float r[4];
#pragma unroll
    for (int j = 0; j < 4; ++j) {
      float v = acc[jj * 4 + j] + ((const float*)&bi)[j];
      v = (v - ((const float*)&mm)[j]) *
              (((const float*)&gg)[j] * rsqrtf(((const float*)&vv)[j] + 1e-5f)) +
          ((const float*)&bb)[j];
      v = v > 0.f ? v : (__expf(v) - 1.f);
      r[j] = v;
    }
    od[jj * 2 + 0] = (unsigned)f2b(r[0]) | ((unsigned)f2b(r[1]) << 16);
    od[jj * 2 + 1] = (unsigned)f2b(r[2]) | ((unsigned)f2b(r[3]) << 16);
  }
  *(uint4*)&outb[((size_t)node << 10) + cb] = make_uint4(od[0], od[1], od[2], od[3]);
}

// ======================= wave-per-node GAT aggregation, H=1, f32 out ==============
__global__ __launch_bounds__(256) void k_aggw1(
    const unsigned short* __restrict__ hpre, const float* __restrict__ aS,
    const float* __restrict__ aD, const int* __restrict__ rowoff,
    const int* __restrict__ csr, const float* __restrict__ bias,
    const float* __restrict__ bn, float* __restrict__ outf) {
  const int wv = threadIdx.x >> 6;
  const int lane = threadIdx.x & 63;
  const int node = blockIdx.x * 4 + wv;
  if (node >= N_NODES) return;

  __shared__ int s_src_all[4][64];
  __shared__ float s_alp_all[4][64];
  int* s_src = s_src_all[wv];
  float* s_alp = s_alp_all[wv];

  const int r0 = rowoff[node];
  const int deg = rowoff[node + 1] - r0;
  const float ad = aD[node];

  float acc[4] = {0.f, 0.f, 0.f, 0.f};

  auto gather = [&](int cnt) {
    int e = 0;
    for (; e + 4 <= cnt; e += 4) {
      uint2 v[4];
      float al[4];
#pragma unroll
      for (int u = 0; u < 4; ++u) {
        const int s = s_src[e + u];
        al[u] = s_alp[e + u];
        v[u] = ((const uint2*)(hpre + ((size_t)s << 8)))[lane];
      }
#pragma unroll
      for (int u = 0; u < 4; ++u) {
        float lo, hi;
        up2(v[u].x, lo, hi); acc[0] += al[u] * lo; acc[1] += al[u] * hi;
        up2(v[u].y, lo, hi); acc[2] += al[u] * lo; acc[3] += al[u] * hi;
      }
    }
    for (; e < cnt; ++e) {
      const int s = s_src[e];
      const float al = s_alp[e];
      const uint2 v = ((const uint2*)(hpre + ((size_t)s << 8)))[lane];
      float lo, hi;
      up2(v.x, lo, hi); acc[0] += al * lo; acc[1] += al * hi;
      up2(v.y, lo, hi); acc[2] += al * lo; acc[3] += al * hi;
    }
  };

  if (deg <= 64) {
    float l0;
    int sE = 0;
    const bool act = lane < deg;
    if (act) {
      sE = csr[r0 + lane];
      l0 = lrelu(aS[sE] + ad);
    } else {
      l0 = NEG_INF;
    }
    float m0 = l0;
#pragma unroll
    for (int off = 32; off; off >>= 1) m0 = fmaxf(m0, __shfl_xor(m0, off));
    float e0 = act ? __expf(l0 - m0) : 0.f;
    float s0 = e0;
#pragma unroll
    for (int off = 32; off; off >>= 1) s0 += __shfl_xor(s0, off);
    if (act) {
      s_src[lane] = sE;
      s_alp[lane] = e0 / (s0 + 1e-16f);
    }
    gather(deg);
  } else {
    float m0 = NEG_INF;
    for (int base = 0; base < deg; base += 64)
      if (base + lane < deg) m0 = fmaxf(m0, lrelu(aS[csr[r0 + base + lane]] + ad));
#pragma unroll
    for (int off = 32; off; off >>= 1) m0 = fmaxf(m0, __shfl_xor(m0, off));
    float s0 = 0.f;
    for (int base = 0; base < deg; base += 64)
      if (base + lane < deg) s0 += __expf(lrelu(aS[csr[r0 + base + lane]] + ad) - m0);
#pragma unroll
    for (int off = 32; off; off >>= 1) s0 += __shfl_xor(s0, off);
    const float d0 = 1.f / (s0 + 1e-16f);
    for (int base = 0; base < deg; base += 64) {
      const int cnt = min(64, deg - base);
      if (lane < cnt) {
        const int s = csr[r0 + base + lane];
        s_src[lane] = s;
        s_alp[lane] = __expf(lrelu(aS[s] + ad) - m0) * d0;
      }
      gather(cnt);
    }
  }

  const int c = lane * 4;
  const float4 bi = *(const float4*)&bias[c];
  const float4 gg = *(const float4*)&bn[c];
  const float4 bb = *(const float4*)&bn[256 + c];
  const float4 mm = *(const float4*)&bn[512 + c];
  const float4 vv = *(const float4*)&bn[768 + c];
  float4 o;
#pragma unroll
  for (int j = 0; j < 4; ++j) {
    float v = acc[j] + ((const float*)&bi)[j];
    v = (v - ((const float*)&mm)[j]) *
            (((const float*)&gg)[j] * rsqrtf(((const float*)&vv)[j] + 1e-5f)) +
        ((const float*)&bb)[j];
    v = v > 0.f ? v : (__expf(v) - 1.f);
    ((float*)&o)[j] = v;
  }
  *(float4*)&outf[((size_t)node << 8) + c] = o;
}

// ======================= graph readout =======================
__global__ __launch_bounds__(256) void k_pool(const float* __restrict__ h,
                                              const int* __restrict__ goff,
                                              float* __restrict__ z) {
  const int g = blockIdx.x;
  const int c = threadIdx.x;
  const int i0 = goff[g], i1 = goff[g + 1];
  float s = 0.f, mx = NEG_INF;
  for (int i = i0; i < i1; ++i) {
    float v = h[(size_t)i * 256 + c];
    s += v;
    mx = fmaxf(mx, v);
  }
  const float cnt = (float)(i1 - i0);
  z[(size_t)g * 768 + c] = s / cnt;
  z[(size_t)g * 768 + 256 + c] = mx;
  z[(size_t)g * 768 + 512 + c] = s;
}

// ======================= fc3 =======================
__global__ __launch_bounds__(64) void k_fc3(const float* __restrict__ z2,
                                            const float* __restrict__ w,
                                            const float* __restrict__ b,
                                            float* __restrict__ out) {
  const int g = blockIdx.x;
  const int lane = threadIdx.x;
  float s = 0.f;
#pragma unroll
  for (int j = 0; j < 4; ++j) {
    int c = lane + 64 * j;
    s += z2[(size_t)g * 256 + c] * w[c];
  }
#pragma unroll
  for (int off = 32; off; off >>= 1) s += __shfl_xor(s, off);
  if (lane == 0) out[g] = s + b[0];
}

// ======================= host launch =======================
extern "C" void kernel_launch(void* const* d_in, const int* in_sizes, int n_in,
                              void* d_out, int out_size, void* d_ws, size_t ws_size,
                              hipStream_t stream) {
  const float* x    = (const float*)d_in[0];
  const int* ei     = (const int*)d_in[1];
  const int* batch  = (const int*)d_in[2];
  const float* W1   = (const float*)d_in[3];
  const float* as1  = (const float*)d_in[4];
  const float* ad1  = (const float*)d_in[5];
  const float* b1   = (const float*)d_in[6];
  const float* bn1  = (const float*)d_in[7];
  const float* W2   = (const float*)d_in[8];
  const float* as2  = (const float*)d_in[9];
  const float* ad2  = (const float*)d_in[10];
  const float* b2   = (const float*)d_in[11];
  const float* bn2  = (const float*)d_in[12];
  const float* W3   = (const float*)d_in[13];
  const float* as3  = (const float*)d_in[14];
  const float* ad3  = (const float*)d_in[15];
  const float* b3   = (const float*)d_in[16];
  const float* bn3  = (const float*)d_in[17];
  const float* fc1w = (const float*)d_in[18];
  const float* fc1b = (const float*)d_in[19];
  const float* bnf1 = (const float*)d_in[20];
  const float* fc2w = (const float*)d_in[21];
  const float* fc2b = (const float*)d_in[22];
  const float* bnf2 = (const float*)d_in[23];
  const float* fc3w = (const float*)d_in[24];
  const float* fc3b = (const float*)d_in[25];
  float* out = (float*)d_out;

  const int* e_src = ei;
  const int* e_dst = ei + N_EDGES;

  char* w = (char*)d_ws;
  auto alloc = [&](size_t bytes) -> void* {
    void* p = (void*)w;
    w += (bytes + 255) & ~(size_t)255;
    return p;
  };
  unsigned short* x_bf  = (unsigned short*)alloc((size_t)N_NODES * 128 * 2);
  unsigned short* xt    = (unsigned short*)alloc((size_t)N_NODES * 512 * 2);
  unsigned short* W1t   = (unsigned short*)alloc((size_t)1024 * 128 * 2);
  unsigned short* W2t   = (unsigned short*)alloc((size_t)1024 * 1024 * 2);
  unsigned short* W3t   = (unsigned short*)alloc((size_t)256 * 1024 * 2);
  unsigned short* hA_bf = (unsigned short*)alloc((size_t)N_NODES * 1024 * 2);
  unsigned short* hB_bf = (unsigned short*)alloc((size_t)N_NODES * 1024 * 2);
  float* hB_f32 = (float*)alloc((size_t)N_NODES * 256 * 4);
  float* aS   = (float*)alloc((size_t)N_NODES * 4 * 4);
  float* aD   = (float*)alloc((size_t)N_NODES * 4 * 4);
  float* wS1  = (float*)alloc((size_t)512 * 4);
  float* wD1  = (float*)alloc((size_t)512 * 4);
  int* deg    = (int*)alloc((size_t)(2 * N_NODES + N_GRAPH) * 4);
  int* cursor = deg + N_NODES;
  int* gcnt   = deg + 2 * N_NODES;
  int* rowoff = (int*)alloc((size_t)(N_NODES + 1) * 4);
  int* goff   = (int*)alloc((size_t)(N_GRAPH + 1) * 4);
  int* csr    = (int*)alloc((size_t)N_EDGES * 4);
  float* z    = (float*)alloc((size_t)N_GRAPH * 768 * 4);
  float* z1   = (float*)alloc((size_t)N_GRAPH * 512 * 4);
  float* z2   = (float*)alloc((size_t)N_GRAPH * 256 * 4);

  hipMemsetAsync(deg, 0, (size_t)(2 * N_NODES + N_GRAPH) * 4, stream);

  // conversions + layer-1 attention mix (independent of CSR build)
  k_convT<<<dim3(1024 / 32, 128 / 32), 256, 0, stream>>>(W1, W1t, 128, 1024);
  k_convT<<<dim3(1024 / 32, 1024 / 32), 256, 0, stream>>>(W2, W2t, 1024, 1024);
  k_convT<<<dim3(256 / 32, 1024 / 32), 256, 0, stream>>>(W3, W3t, 1024, 256);
  k_wmix<<<2, 256, 0, stream>>>(W1, as1, ad1, wS1, wD1);
  k_prep_x<<<(N_NODES + 3) / 4, 256, 0, stream>>>(x, wS1, wD1, x_bf, aS, aD);

  // CSR build (by destination) + graph offsets
  k_count<<<(N_EDGES + 255) / 256, 256, 0, stream>>>(e_dst, batch, deg, gcnt);
  k_scan2<<<1, 1024, 0, stream>>>(deg, rowoff, N_NODES, gcnt, goff, N_GRAPH);
  k_fill<<<(N_EDGES + 255) / 256, 256, 0, stream>>>(e_src, e_dst, rowoff, cursor, csr);
  k_sortseg<<<(N_NODES + 3) / 4, 256, 0, stream>>>(rowoff, csr);

  const int mt = (N_NODES + 127) / 128;  // 79
  const int mt8 = 80;                     // pad rows-tiles to multiple of 8 for swizzle
  const int nb2 = (N_NODES + 1) / 2;
  const int nb4 = (N_NODES + 3) / 4;

  // ---- layer 1: aggregate in x-space, then block-diagonal GEMM (fused epi) ----
  k_aggx<<<nb4, 256, 0, stream>>>(x_bf, aS, aD, rowoff, csr, xt);
  k_gemm_l1<<<dim3(8, mt), 256, 0, stream>>>(xt, W1t, hB_bf, N_NODES, b1, bn1);

  // ---- layer 2 ----
  k_gemm_bf16<<<dim3(8, mt8), 256, 0, stream>>>(
      hB_bf, 1024, W2t, 1024, hA_bf, 1024, N_NODES, 1024, 1024, 8);
  k_att<4><<<(N_NODES * 4 + 3) / 4, 256, 0, stream>>>(hA_bf, as2, ad2, aS, aD);
  k_aggw4<<<nb2, 256, 0, stream>>>(hA_bf, aS, aD, rowoff, csr, b2, bn2, hB_bf);

  // ---- layer 3 ----
  k_gemm_bf16<<<dim3(2, mt8), 256, 0, stream>>>(
      hB_bf, 1024, W3t, 1024, hA_bf, 256, N_NODES, 256, 1024, 2);
  k_att<1><<<(N_NODES + 3) / 4, 256, 0, stream>>>(hA_bf, as3, ad3, aS, aD);
  k_aggw1<<<nb4, 256, 0, stream>>>(hA_bf, aS, aD, rowoff, csr, b3, bn3, hB_f32);

  // ---- readout + MLP head ----
  k_pool<<<N_GRAPH, 256, 0, stream>>>(hB_f32, goff, z);
  k_head_fc<768, 512><<<dim3(512 / 64, N_GRAPH / 8), 256, 0, stream>>>(z, fc1w, z1, fc1b, bnf1);
  k_head_fc<512, 256><<<dim3(256 / 64, N_GRAPH / 8), 256, 0, stream>>>(z1, fc2w, z2, fc2b, bnf2);
  k_fc3<<<N_GRAPH, 64, 0, stream>>>(z2, fc3w, fc3b, out);
}

// Round 17
// 303.804 us; speedup vs baseline: 1.0433x; 1.0433x over previous
//
#include <hip/hip_runtime.h>
#include <math.h>

#define N_NODES 10000
#define N_EDGES 160000
#define N_GRAPH 512

#define NEG_INF (-1e30f)

typedef __attribute__((ext_vector_type(8))) short s16x8;
typedef __attribute__((ext_vector_type(4))) float f32x4;

__device__ __forceinline__ unsigned short f2b(float f) {
  union { float f; unsigned u; } c{f};
  unsigned u = c.u;
  return (unsigned short)((u + 0x7fff + ((u >> 16) & 1)) >> 16);
}
__device__ __forceinline__ float b2f(unsigned short h) {
  union { unsigned u; float f; } c{(unsigned)h << 16};
  return c.f;
}
__device__ __forceinline__ void up2(unsigned d, float& lo, float& hi) {
  union { unsigned u; float f; } a{d << 16}, b{d & 0xffff0000u};
  lo = a.f; hi = b.f;
}
__device__ __forceinline__ float lrelu(float x) { return x > 0.f ? x : 0.2f * x; }

#define GLL16(gp, lp)                                                          \
  __builtin_amdgcn_global_load_lds(                                            \
      (const __attribute__((address_space(1))) unsigned int*)(gp),             \
      (__attribute__((address_space(3))) unsigned int*)(lp), 16, 0, 0)

// ======================= CSR build =======================
__global__ void k_count(const int* __restrict__ dst, const int* __restrict__ batch,
                        int* __restrict__ deg, int* __restrict__ gcnt) {
  int i = blockIdx.x * 256 + threadIdx.x;
  if (i < N_EDGES) atomicAdd(&deg[dst[i]], 1);
  if (i < N_NODES) atomicAdd(&gcnt[batch[i]], 1);
}

// two exclusive scans in one launch (single block)
__global__ void k_scan2(const int* __restrict__ in1, int* __restrict__ out1, int n1,
                        const int* __restrict__ in2, int* __restrict__ out2, int n2) {
  __shared__ int buf[1024];
  __shared__ int carry_s;
#pragma unroll 1
  for (int pass = 0; pass < 2; ++pass) {
    const int* in = pass ? in2 : in1;
    int* out = pass ? out2 : out1;
    const int n = pass ? n2 : n1;
    if (threadIdx.x == 0) carry_s = 0;
    __syncthreads();
    for (int base = 0; base < n; base += 1024) {
      int i = base + (int)threadIdx.x;
      int v = (i < n) ? in[i] : 0;
      buf[threadIdx.x] = v;
      __syncthreads();
      for (int off = 1; off < 1024; off <<= 1) {
        int t = (threadIdx.x >= (unsigned)off) ? buf[threadIdx.x - off] : 0;
        __syncthreads();
        buf[threadIdx.x] += t;
        __syncthreads();
      }
      int carry = carry_s;
      if (i < n) out[i] = carry + buf[threadIdx.x] - v;
      __syncthreads();
      if (threadIdx.x == 0) carry_s = carry + buf[1023];
      __syncthreads();
    }
    if (threadIdx.x == 0) out[n] = carry_s;
    __syncthreads();
  }
}

__global__ void k_fill(const int* __restrict__ src, const int* __restrict__ dst,
                       const int* __restrict__ rowoff, int* __restrict__ cursor,
                       int* __restrict__ csr) {
  int e = blockIdx.x * 256 + threadIdx.x;
  if (e < N_EDGES) {
    int d = dst[e];
    int p = atomicAdd(&cursor[d], 1);
    csr[rowoff[d] + p] = src[e];
  }
}

__global__ __launch_bounds__(256) void k_sortseg(const int* __restrict__ rowoff,
                                                 int* __restrict__ vals) {
  const int node = blockIdx.x * 4 + (threadIdx.x >> 6);
  if (node >= N_NODES) return;
  const int lane = threadIdx.x & 63;
  const int a = rowoff[node], b = rowoff[node + 1];
  const int deg = b - a;
  if (deg <= 1) return;
  if (deg <= 64) {
    int v = (lane < deg) ? vals[a + lane] : 0x7fffffff;
#pragma unroll
    for (int ph = 0; ph < 64; ++ph) {
      const int par = ph & 1;
      const bool left = ((lane & 1) == par);
      const int partner = left ? lane + 1 : lane - 1;
      const int pv = __shfl(v, partner & 63);
      if (partner >= 0 && partner < 64) v = left ? min(v, pv) : max(v, pv);
    }
    if (lane < deg) vals[a + lane] = v;
  } else if (lane == 0) {
    for (int p = a + 1; p < b; ++p) {
      int v = vals[p];
      int q = p - 1;
      while (q >= a && vals[q] > v) { vals[q + 1] = vals[q]; --q; }
      vals[q + 1] = v;
    }
  }
}

// ======================= conversions =======================
__global__ __launch_bounds__(256) void k_convT(const float* __restrict__ in,
                                               unsigned short* __restrict__ out,
                                               int K, int M) {
  __shared__ float t[32][33];
  const int mb = blockIdx.x * 32, kb = blockIdx.y * 32;
  const int tx = threadIdx.x & 31, ty = threadIdx.x >> 5;
#pragma unroll
  for (int r = ty; r < 32; r += 8) t[r][tx] = in[(size_t)(kb + r) * M + mb + tx];
  __syncthreads();
#pragma unroll
  for (int r = ty; r < 32; r += 8)
    out[(size_t)(mb + r) * K + kb + tx] = f2b(t[tx][r]);
}

// wS[f][h] = sum_c W[f, h*256+c] * att[h*256+c]   (layer-1 rank-1 mix)
__global__ void k_wmix(const float* __restrict__ W, const float* __restrict__ attS,
                       const float* __restrict__ attD, float* __restrict__ wS,
                       float* __restrict__ wD) {
  const int i = blockIdx.x * 256 + threadIdx.x;
  if (i >= 512) return;
  const int f = i >> 2, h = i & 3;
  const float* wrow = W + (size_t)f * 1024 + h * 256;
  const float* as = attS + h * 256;
  const float* ad = attD + h * 256;
  float s = 0.f, d = 0.f;
  for (int c = 0; c < 256; ++c) {
    const float w = wrow[c];
    s += w * as[c];
    d += w * ad[c];
  }
  wS[f * 4 + h] = s;
  wD[f * 4 + h] = d;
}

// fused: x -> x_bf (bf16) AND aS/aD = x @ wS/wD. 4 nodes/block, wave per node.
__global__ __launch_bounds__(256) void k_prep_x(const float* __restrict__ x,
                                                const float* __restrict__ wS,
                                                const float* __restrict__ wD,
                                                unsigned short* __restrict__ x_bf,
                                                float* __restrict__ aS,
                                                float* __restrict__ aD) {
  __shared__ float sS[128][4], sD[128][4];
  const int tid = threadIdx.x;
  for (int i = tid; i < 512; i += 256) {
    sS[i >> 2][i & 3] = wS[i];
    sD[i >> 2][i & 3] = wD[i];
  }
  __syncthreads();
  const int node = blockIdx.x * 4 + (tid >> 6);
  if (node >= N_NODES) return;
  const int lane = tid & 63;
  const float2 xv = ((const float2*)(x + (size_t)node * 128))[lane];
  const unsigned o = (unsigned)f2b(xv.x) | ((unsigned)f2b(xv.y) << 16);
  ((unsigned*)x_bf)[(size_t)node * 64 + lane] = o;
  const float4 s0 = *(const float4*)sS[lane * 2];
  const float4 s1 = *(const float4*)sS[lane * 2 + 1];
  const float4 d0 = *(const float4*)sD[lane * 2];
  const float4 d1 = *(const float4*)sD[lane * 2 + 1];
  float a0 = xv.x * s0.x + xv.y * s1.x;
  float a1 = xv.x * s0.y + xv.y * s1.y;
  float a2 = xv.x * s0.z + xv.y * s1.z;
  float a3 = xv.x * s0.w + xv.y * s1.w;
  float b0 = xv.x * d0.x + xv.y * d1.x;
  float b1 = xv.x * d0.y + xv.y * d1.y;
  float b2 = xv.x * d0.z + xv.y * d1.z;
  float b3 = xv.x * d0.w + xv.y * d1.w;
#pragma unroll
  for (int off = 32; off; off >>= 1) {
    a0 += __shfl_xor(a0, off); a1 += __shfl_xor(a1, off);
    a2 += __shfl_xor(a2, off); a3 += __shfl_xor(a3, off);
    b0 += __shfl_xor(b0, off); b1 += __shfl_xor(b1, off);
    b2 += __shfl_xor(b2, off); b3 += __shfl_xor(b3, off);
  }
  if (lane == 0) {
    *(float4*)&aS[(size_t)node * 4] = make_float4(a0, a1, a2, a3);
    *(float4*)&aD[(size_t)node * 4] = make_float4(b0, b1, b2, b3);
  }
}

// x-space aggregation for layer 1 (working set 2.5MB, L2-fit; softmax fused)
__global__ __launch_bounds__(256) void k_aggx(
    const unsigned short* __restrict__ x_bf, const float* __restrict__ aS,
    const float* __restrict__ aD, const int* __restrict__ rowoff,
    const int* __restrict__ csr, unsigned short* __restrict__ xt) {
  const int wv = threadIdx.x >> 6;
  const int lane = threadIdx.x & 63;
  const int node = blockIdx.x * 4 + wv;
  if (node >= N_NODES) return;

  __shared__ int s_src_all[4][64];
  __shared__ float s_alp_all[4][64][4];
  int* s_src = s_src_all[wv];
  float (*s_alp)[4] = s_alp_all[wv];

  const int r0 = rowoff[node];
  const int deg = rowoff[node + 1] - r0;
  const float4 ad4 = *(const float4*)&aD[(size_t)node * 4];

  float acc[8];
#pragma unroll
  for (int j = 0; j < 8; ++j) acc[j] = 0.f;

  auto gather = [&](int cnt) {
    int e = 0;
    for (; e + 4 <= cnt; e += 4) {
      unsigned v[4];
      float4 al[4];
#pragma unroll
      for (int u = 0; u < 4; ++u) {
        const int s = s_src[e + u];
        al[u] = *(const float4*)s_alp[e + u];
        v[u] = ((const unsigned*)(x_bf + ((size_t)s << 7)))[lane];
      }
#pragma unroll
      for (int u = 0; u < 4; ++u) {
        float lo, hi;
        up2(v[u], lo, hi);
        acc[0] += al[u].x * lo; acc[1] += al[u].x * hi;
        acc[2] += al[u].y * lo; acc[3] += al[u].y * hi;
        acc[4] += al[u].z * lo; acc[5] += al[u].z * hi;
        acc[6] += al[u].w * lo; acc[7] += al[u].w * hi;
      }
    }
    for (; e < cnt; ++e) {
      const int s = s_src[e];
      const float4 al = *(const float4*)s_alp[e];
      const unsigned v = ((const unsigned*)(x_bf + ((size_t)s << 7)))[lane];
      float lo, hi;
      up2(v, lo, hi);
      acc[0] += al.x * lo; acc[1] += al.x * hi;
      acc[2] += al.y * lo; acc[3] += al.y * hi;
      acc[4] += al.z * lo; acc[5] += al.z * hi;
      acc[6] += al.w * lo; acc[7] += al.w * hi;
    }
  };

  if (deg <= 64) {
    float l0, l1, l2, l3;
    int sE = 0;
    const bool act = lane < deg;
    if (act) {
      sE = csr[r0 + lane];
      const float4 sv = *(const float4*)&aS[(size_t)sE * 4];
      l0 = lrelu(sv.x + ad4.x);
      l1 = lrelu(sv.y + ad4.y);
      l2 = lrelu(sv.z + ad4.z);
      l3 = lrelu(sv.w + ad4.w);
    } else {
      l0 = l1 = l2 = l3 = NEG_INF;
    }
    float m0 = l0, m1 = l1, m2 = l2, m3 = l3;
#pragma unroll
    for (int off = 32; off; off >>= 1) {
      m0 = fmaxf(m0, __shfl_xor(m0, off));
      m1 = fmaxf(m1, __shfl_xor(m1, off));
      m2 = fmaxf(m2, __shfl_xor(m2, off));
      m3 = fmaxf(m3, __shfl_xor(m3, off));
    }
    float e0 = act ? __expf(l0 - m0) : 0.f;
    float e1 = act ? __expf(l1 - m1) : 0.f;
    float e2 = act ? __expf(l2 - m2) : 0.f;
    float e3 = act ? __expf(l3 - m3) : 0.f;
    float s0 = e0, s1 = e1, s2 = e2, s3 = e3;
#pragma unroll
    for (int off = 32; off; off >>= 1) {
      s0 += __shfl_xor(s0, off);
      s1 += __shfl_xor(s1, off);
      s2 += __shfl_xor(s2, off);
      s3 += __shfl_xor(s3, off);
    }
    if (act) {
      s_src[lane] = sE;
      s_alp[lane][0] = e0 / (s0 + 1e-16f);
      s_alp[lane][1] = e1 / (s1 + 1e-16f);
      s_alp[lane][2] = e2 / (s2 + 1e-16f);
      s_alp[lane][3] = e3 / (s3 + 1e-16f);
    }
    gather(deg);
  } else {
    auto logits = [&](int idx, float& a, float& b, float& c, float& d, int& s) {
      s = csr[r0 + idx];
      const float4 sv = *(const float4*)&aS[(size_t)s * 4];
      a = lrelu(sv.x + ad4.x);
      b = lrelu(sv.y + ad4.y);
      c = lrelu(sv.z + ad4.z);
      d = lrelu(sv.w + ad4.w);
    };
    float m0 = NEG_INF, m1 = NEG_INF, m2 = NEG_INF, m3 = NEG_INF;
    for (int base = 0; base < deg; base += 64) {
      if (base + lane < deg) {
        float a, b, c, d; int s;
        logits(base + lane, a, b, c, d, s);
        m0 = fmaxf(m0, a); m1 = fmaxf(m1, b); m2 = fmaxf(m2, c); m3 = fmaxf(m3, d);
      }
    }
#pragma unroll
    for (int off = 32; off; off >>= 1) {
      m0 = fmaxf(m0, __shfl_xor(m0, off));
      m1 = fmaxf(m1, __shfl_xor(m1, off));
      m2 = fmaxf(m2, __shfl_xor(m2, off));
      m3 = fmaxf(m3, __shfl_xor(m3, off));
    }
    float s0 = 0.f, s1 = 0.f, s2 = 0.f, s3 = 0.f;
    for (int base = 0; base < deg; base += 64) {
      if (base + lane < deg) {
        float a, b, c, d; int s;
        logits(base + lane, a, b, c, d, s);
        s0 += __expf(a - m0); s1 += __expf(b - m1);
        s2 += __expf(c - m2); s3 += __expf(d - m3);
      }
    }
#pragma unroll
    for (int off = 32; off; off >>= 1) {
      s0 += __shfl_xor(s0, off);
      s1 += __shfl_xor(s1, off);
      s2 += __shfl_xor(s2, off);
      s3 += __shfl_xor(s3, off);
    }
    const float d0 = 1.f / (s0 + 1e-16f), d1 = 1.f / (s1 + 1e-16f);
    const float d2 = 1.f / (s2 + 1e-16f), d3 = 1.f / (s3 + 1e-16f);
    for (int base = 0; base < deg; base += 64) {
      const int cnt = min(64, deg - base);
      if (lane < cnt) {
        float a, b, c, d; int s;
        logits(base + lane, a, b, c, d, s);
        s_src[lane] = s;
        s_alp[lane][0] = __expf(a - m0) * d0;
        s_alp[lane][1] = __expf(b - m1) * d1;
        s_alp[lane][2] = __expf(c - m2) * d2;
        s_alp[lane][3] = __expf(d - m3) * d3;
      }
      gather(cnt);
    }
  }

#pragma unroll
  for (int h = 0; h < 4; ++h) {
    const unsigned o = (unsigned)f2b(acc[h * 2]) | ((unsigned)f2b(acc[h * 2 + 1]) << 16);
    ((unsigned*)xt)[(size_t)node * 256 + h * 64 + lane] = o;
  }
}

// ======================= bf16 MFMA GEMM (strided, XCD-swizzled, BK=32) ============
__global__ __launch_bounds__(256) void k_gemm_bf16(
    const unsigned short* __restrict__ A, int lda,
    const unsigned short* __restrict__ Bt, int ldb,
    unsigned short* __restrict__ Cbf, int ldc,
    int M, int N, int K, int nbx) {
  __shared__ unsigned short As[128 * 32];
  __shared__ unsigned short Bs[128 * 32];
  const int tid = threadIdx.x;
  const int lane = tid & 63, wave = tid >> 6;
  const int wr = wave >> 1, wc = wave & 1;

  // XCD-aware swizzle over the linear block id (nwg % 8 == 0 guaranteed by caller pad)
  const int nwg = nbx * gridDim.y;
  int bid = blockIdx.y * nbx + blockIdx.x;
  {
    const int per = nwg >> 3;  // nwg/8
    const int xcd = bid & 7, idx = bid >> 3;
    bid = xcd * per + idx;
  }
  const int by = bid / nbx, bx = bid % nbx;
  const int m0 = by * 128, n0 = bx * 128;

  f32x4 acc[4][4];
#pragma unroll
  for (int i = 0; i < 4; ++i)
#pragma unroll
    for (int j = 0; j < 4; ++j) acc[i][j] = (f32x4){0.f, 0.f, 0.f, 0.f};

  const int l4 = lane >> 2;
  const int kp8 = (lane & 3) * 8;
  int rA0 = m0 + wave * 32 + l4;
  int rA1 = rA0 + 16;
  rA0 = min(rA0, M - 1);
  rA1 = min(rA1, M - 1);
  const int rB0 = n0 + wave * 32 + l4;
  const int rB1 = rB0 + 16;
  const unsigned short* pA0 = A + (size_t)rA0 * lda + kp8;
  const unsigned short* pA1 = A + (size_t)rA1 * lda + kp8;
  const unsigned short* pB0 = Bt + (size_t)rB0 * ldb + kp8;
  const unsigned short* pB1 = Bt + (size_t)rB1 * ldb + kp8;
  unsigned short* lA = As + wave * 1024;
  unsigned short* lB = Bs + wave * 1024;

  const int fr = lane & 15, kg = (lane >> 4) * 8;

  for (int kb = 0; kb < K; kb += 32) {
    GLL16(pA0 + kb, lA);
    GLL16(pA1 + kb, lA + 512);
    GLL16(pB0 + kb, lB);
    GLL16(pB1 + kb, lB + 512);
    __syncthreads();

    s16x8 a[4], b[4];
#pragma unroll
    for (int m = 0; m < 4; ++m)
      a[m] = *(const s16x8*)&As[(wr * 64 + m * 16 + fr) * 32 + kg];
#pragma unroll
    for (int n = 0; n < 4; ++n)
      b[n] = *(const s16x8*)&Bs[(wc * 64 + n * 16 + fr) * 32 + kg];
#pragma unroll
    for (int m = 0; m < 4; ++m)
#pragma unroll
      for (int n = 0; n < 4; ++n)
        acc[m][n] = __builtin_amdgcn_mfma_f32_16x16x32_bf16(a[m], b[n], acc[m][n], 0, 0, 0);
    __syncthreads();
  }

  const int frow = (lane >> 4) * 4;
#pragma unroll
  for (int m = 0; m < 4; ++m) {
#pragma unroll
    for (int r = 0; r < 4; ++r) {
      const int row = m0 + wr * 64 + m * 16 + frow + r;
      if (row < M) {
#pragma unroll
        for (int n = 0; n < 4; ++n) {
          const int col = n0 + wc * 64 + n * 16 + fr;
          Cbf[(size_t)row * ldc + col] = f2b(acc[m][n][r]);
        }
      }
    }
  }
}

// ======================= layer-1 block-diagonal GEMM, fused epilogue =============
__global__ __launch_bounds__(256) void k_gemm_l1(
    const unsigned short* __restrict__ xt,    // [N][512]
    const unsigned short* __restrict__ W1t,   // [1024][128]
    unsigned short* __restrict__ Cbf,         // [N][1024]
    int M, const float* __restrict__ bias, const float* __restrict__ bn) {
  constexpr int K = 128, lda = 512, ldb = 128, ldc = 1024;
  __shared__ unsigned short As[128 * 32];
  __shared__ unsigned short Bs[128 * 32];
  const int tid = threadIdx.x;
  const int lane = tid & 63, wave = tid >> 6;
  const int wr = wave >> 1, wc = wave & 1;
  const int bx = blockIdx.x;
  const int h = bx >> 1;
  const int n0 = (bx & 1) * 128;
  const int colbase = h * 256;
  const int m0 = blockIdx.y * 128;
  const unsigned short* A = xt + h * 128;
  const unsigned short* Bt = W1t + (size_t)colbase * ldb;

  f32x4 acc[4][4];
#pragma unroll
  for (int i = 0; i < 4; ++i)
#pragma unroll
    for (int j = 0; j < 4; ++j) acc[i][j] = (f32x4){0.f, 0.f, 0.f, 0.f};

  const int l4 = lane >> 2;
  const int kp8 = (lane & 3) * 8;
  int rA0 = m0 + wave * 32 + l4;
  int rA1 = rA0 + 16;
  rA0 = min(rA0, M - 1);
  rA1 = min(rA1, M - 1);
  const int rB0 = n0 + wave * 32 + l4;
  const int rB1 = rB0 + 16;
  const unsigned short* pA0 = A + (size_t)rA0 * lda + kp8;
  const unsigned short* pA1 = A + (size_t)rA1 * lda + kp8;
  const unsigned short* pB0 = Bt + (size_t)rB0 * ldb + kp8;
  const unsigned short* pB1 = Bt + (size_t)rB1 * ldb + kp8;
  unsigned short* lA = As + wave * 1024;
  unsigned short* lB = Bs + wave * 1024;

  const int fr = lane & 15, kg = (lane >> 4) * 8;

  for (int kb = 0; kb < K; kb += 32) {
    GLL16(pA0 + kb, lA);
    GLL16(pA1 + kb, lA + 512);
    GLL16(pB0 + kb, lB);
    GLL16(pB1 + kb, lB + 512);
    __syncthreads();

    s16x8 a[4], b[4];
#pragma unroll
    for (int m = 0; m < 4; ++m)
      a[m] = *(const s16x8*)&As[(wr * 64 + m * 16 + fr) * 32 + kg];
#pragma unroll
    for (int n = 0; n < 4; ++n)
      b[n] = *(const s16x8*)&Bs[(wc * 64 + n * 16 + fr) * 32 + kg];
#pragma unroll
    for (int m = 0; m < 4; ++m)
#pragma unroll
      for (int n = 0; n < 4; ++n)
        acc[m][n] = __builtin_amdgcn_mfma_f32_16x16x32_bf16(a[m], b[n], acc[m][n], 0, 0, 0);
    __syncthreads();
  }

  const int frow = (lane >> 4) * 4;
#pragma unroll
  for (int m = 0; m < 4; ++m) {
#pragma unroll
    for (int r = 0; r < 4; ++r) {
      const int row = m0 + wr * 64 + m * 16 + frow + r;
      if (row < M) {
#pragma unroll
        for (int n = 0; n < 4; ++n) {
          const int col = n0 + wc * 64 + n * 16 + fr;
          const int gcol = colbase + col;
          float v = acc[m][n][r] + bias[gcol];
          const float g = bn[gcol], b = bn[1024 + gcol];
          const float mu = bn[2048 + gcol], var = bn[3072 + gcol];
          v = (v - mu) * (g * rsqrtf(var + 1e-5f)) + b;
          v = v > 0.f ? v : (__expf(v) - 1.f);
          Cbf[(size_t)row * ldc + gcol] = f2b(v);
        }
      }
    }
  }
}

// ======================= head MLP fp32 GEMM =======================
template <int K, int M>
__global__ __launch_bounds__(256) void k_head_fc(
    const float* __restrict__ A, const float* __restrict__ W,
    float* __restrict__ C, const float* __restrict__ bias,
    const float* __restrict__ bn) {
  constexpr int KQ = K / 4;
  __shared__ float Ap[8 * K];
  __shared__ float part[4][8][64];
  const int tid = threadIdx.x;
  const int g0 = blockIdx.y * 8;
  const int m0 = blockIdx.x * 64;
  const int c = tid & 63;
  const int q = tid >> 6;

  for (int i = tid; i < 8 * K / 4; i += 256)
    ((float4*)Ap)[i] = ((const float4*)(A + (size_t)g0 * K))[i];
  __syncthreads();

  float acc[8];
#pragma unroll
  for (int r = 0; r < 8; ++r) acc[r] = 0.f;

  const float* Wc = W + m0 + c;
  const int k0 = q * KQ;
  for (int k = k0; k < k0 + KQ; k += 4) {
    float wv[4];
#pragma unroll
    for (int u = 0; u < 4; ++u) wv[u] = Wc[(size_t)(k + u) * M];
#pragma unroll
    for (int r = 0; r < 8; ++r) {
      const float4 a4 = *(const float4*)&Ap[r * K + k];
      acc[r] += a4.x * wv[0] + a4.y * wv[1] + a4.z * wv[2] + a4.w * wv[3];
    }
  }

#pragma unroll
  for (int r = 0; r < 8; ++r) part[q][r][c] = acc[r];
  __syncthreads();

  for (int i = tid; i < 512; i += 256) {
    const int r = i >> 6, cc = i & 63;
    float v = part[0][r][cc] + part[1][r][cc] + part[2][r][cc] + part[3][r][cc];
    const int gc = m0 + cc;
    v += bias[gc];
    const float g = bn[gc], b = bn[M + gc], mu = bn[2 * M + gc], var = bn[3 * M + gc];
    v = (v - mu) * (g * rsqrtf(var + 1e-5f)) + b;
    v = fmaxf(v, 0.f);
    C[(size_t)(g0 + r) * M + gc] = v;
  }
}

// ======================= attention scores from h (layers 2,3) =====================
template <int HEADS>
__global__ __launch_bounds__(256) void k_att(const unsigned short* __restrict__ h,
                                             const float* __restrict__ att_s,
                                             const float* __restrict__ att_d,
                                             float* __restrict__ aS,
                                             float* __restrict__ aD) {
  const int pair = blockIdx.x * 4 + (threadIdx.x >> 6);
  if (pair >= N_NODES * HEADS) return;
  const int node = pair / HEADS, hd = pair % HEADS;
  const int lane = threadIdx.x & 63;
  const unsigned short* row = h + (size_t)node * HEADS * 256 + hd * 256;
  const ushort4 v = *(const ushort4*)&row[lane * 4];
  const float4 s4 = *(const float4*)&att_s[hd * 256 + lane * 4];
  const float4 d4 = *(const float4*)&att_d[hd * 256 + lane * 4];
  float ss = b2f(v.x) * s4.x + b2f(v.y) * s4.y + b2f(v.z) * s4.z + b2f(v.w) * s4.w;
  float sd = b2f(v.x) * d4.x + b2f(v.y) * d4.y + b2f(v.z) * d4.z + b2f(v.w) * d4.w;
#pragma unroll
  for (int off = 32; off; off >>= 1) {
    ss += __shfl_xor(ss, off);
    sd += __shfl_xor(sd, off);
  }
  if (lane == 0) {
    aS[pair] = ss;
    aD[pair] = sd;
  }
}

// ======================= half-row-wave GAT aggregation, H=4 (layer 2) =============
__global__ __launch_bounds__(256) void k_aggw4(
    const unsigned short* __restrict__ hpre, const float* __restrict__ aS,
    const float* __restrict__ aD, const int* __restrict__ rowoff,
    const int* __restrict__ csr, const float* __restrict__ bias,
    const float* __restrict__ bn, unsigned short* __restrict__ outb) {
  const int wv = threadIdx.x >> 6;
  const int lane = threadIdx.x & 63;
  const int node = blockIdx.x * 2 + (wv >> 1);
  const int half = wv & 1;
  if (node >= N_NODES) return;

  __shared__ int s_src_all[4][64];
  __shared__ float s_alp_all[4][64][2];
  int* s_src = s_src_all[wv];
  float (*s_alp)[2] = s_alp_all[wv];

  const int r0 = rowoff[node];
  const int deg = rowoff[node + 1] - r0;
  const float2 ad2 = *(const float2*)&aD[(size_t)node * 4 + half * 2];

  float acc[8];
#pragma unroll
  for (int j = 0; j < 8; ++j) acc[j] = 0.f;

  const int hg = lane >> 5;
  const size_t choff = (size_t)half * 512;

  auto gather = [&](int cnt) {
    int e = 0;
    for (; e + 4 <= cnt; e += 4) {
      uint4 v[4];
      float al[4];
#pragma unroll
      for (int u = 0; u < 4; ++u) {
        const int s = s_src[e + u];
        al[u] = s_alp[e + u][hg];
        v[u] = ((const uint4*)(hpre + ((size_t)s << 10) + choff))[lane];
      }
#pragma unroll
      for (int u = 0; u < 4; ++u) {
        float lo, hi;
        up2(v[u].x, lo, hi); acc[0] += al[u] * lo; acc[1] += al[u] * hi;
        up2(v[u].y, lo, hi); acc[2] += al[u] * lo; acc[3] += al[u] * hi;
        up2(v[u].z, lo, hi); acc[4] += al[u] * lo; acc[5] += al[u] * hi;
        up2(v[u].w, lo, hi); acc[6] += al[u] * lo; acc[7] += al[u] * hi;
      }
    }
    for (; e < cnt; ++e) {
      const int s = s_src[e];
      const float al = s_alp[e][hg];
      const uint4 v = ((const uint4*)(hpre + ((size_t)s << 10) + choff))[lane];
      float lo, hi;
      up2(v.x, lo, hi); acc[0] += al * lo; acc[1] += al * hi;
      up2(v.y, lo, hi); acc[2] += al * lo; acc[3] += al * hi;
      up2(v.z, lo, hi); acc[4] += al * lo; acc[5] += al * hi;
      up2(v.w, lo, hi); acc[6] += al * lo; acc[7] += al * hi;
    }
  };

  if (deg <= 64) {
    float la, lb;
    int sE = 0;
    const bool act = lane < deg;
    if (act) {
      sE = csr[r0 + lane];
      const float2 sv = *(const float2*)&aS[(size_t)sE * 4 + half * 2];
      la = lrelu(sv.x + ad2.x);
      lb = lrelu(sv.y + ad2.y);
    } else {
      la = lb = NEG_INF;
    }
    float ma = la, mb = lb;
#pragma unroll
    for (int off = 32; off; off >>= 1) {
      ma = fmaxf(ma, __shfl_xor(ma, off));
      mb = fmaxf(mb, __shfl_xor(mb, off));
    }
    float ea = act ? __expf(la - ma) : 0.f;
    float eb = act ? __expf(lb - mb) : 0.f;
    float sa = ea, sb = eb;
#pragma unroll
    for (int off = 32; off; off >>= 1) {
      sa += __shfl_xor(sa, off);
      sb += __shfl_xor(sb, off);
    }
    if (act) {
      s_src[lane] = sE;
      s_alp[lane][0] = ea / (sa + 1e-16f);
      s_alp[lane][1] = eb / (sb + 1e-16f);
    }
    gather(deg);
  } else {
    auto logits = [&](int idx, float& a, float& b, int& s) {
      s = csr[r0 + idx];
      const float2 sv = *(const float2*)&aS[(size_t)s * 4 + half * 2];
      a = lrelu(sv.x + ad2.x);
      b = lrelu(sv.y + ad2.y);
    };
    float ma = NEG_INF, mb = NEG_INF;
    for (int base = 0; base < deg; base += 64) {
      if (base + lane < deg) {
        float a, b; int s;
        logits(base + lane, a, b, s);
        ma = fmaxf(ma, a); mb = fmaxf(mb, b);
      }
    }
#pragma unroll
    for (int off = 32; off; off >>= 1) {
      ma = fmaxf(ma, __shfl_xor(ma, off));
      mb = fmaxf(mb, __shfl_xor(mb, off));
    }
    float sa = 0.f, sb = 0.f;
    for (int base = 0; base < deg; base += 64) {
      if (base + lane < deg) {
        float a, b; int s;
        logits(base + lane, a, b, s);
        sa += __expf(a - ma); sb += __expf(b - mb);
      }
    }
#pragma unroll
    for (int off = 32; off; off >>= 1) {
      sa += __shfl_xor(sa, off);
      sb += __shfl_xor(sb, off);
    }
    const float da = 1.f / (sa + 1e-16f), db = 1.f / (sb + 1e-16f);
    for (int base = 0; base < deg; base += 64) {
      const int cnt = min(64, deg - base);
      if (lane < cnt) {
        float a, b; int s;
        logits(base + lane, a, b, s);
        s_src[lane] = s;
        s_alp[lane][0] = __expf(a - ma) * da;
        s_alp[lane][1] = __expf(b - mb) * db;
      }
      gather(cnt);
    }
  }

  const int cb = half * 512 + lane * 8;
  unsigned od[4];
#pragma unroll
  for (int jj = 0; jj < 2; ++jj) {
    const float4 bi = *(const float4*)&bias[cb + jj * 4];
    const float4 gg = *(const float4*)&bn[cb + jj * 4];
    const float4 bb = *(const float4*)&bn[1024 + cb + jj * 4];
    const float4 mm = *(const float4*)&bn[2048 + cb + jj * 4];
    const float4 vv = *(const float4*)&bn[3072 + cb + jj * 4];
    float r[4];
#pragma unroll
    for (int j = 0; j < 4; ++j) {
      float v = acc[jj * 4 + j] + ((const float*)&bi)[j];
      v = (v - ((const float*)&mm)[j]) *
              (((const float*)&gg)[j] * rsqrtf(((const float*)&vv)[j] + 1e-5f)) +
          ((const float*)&bb)[j];
      v = v > 0.f ? v : (__expf(v) - 1.f);
      r[j] = v;
    }
    od[jj * 2 + 0] = (unsigned)f2b(r[0]) | ((unsigned)f2b(r[1]) << 16);
    od[jj * 2 + 1] = (unsigned)f2b(r[2]) | ((unsigned)f2b(r[3]) << 16);
  }
  *(uint4*)&outb[((size_t)node << 10) + cb] = make_uint4(od[0], od[1], od[2], od[3]);
}

// ======================= wave-per-node GAT aggregation, H=1, f32 out ==============
__global__ __launch_bounds__(256) void k_aggw1(
    const unsigned short* __restrict__ hpre, const float* __restrict__ aS,
    const float* __restrict__ aD, const int* __restrict__ rowoff,
    const int* __restrict__ csr, const float* __restrict__ bias,
    const float* __restrict__ bn, float* __restrict__ outf) {
  const int wv = threadIdx.x >> 6;
  const int lane = threadIdx.x & 63;
  const int node = blockIdx.x * 4 + wv;
  if (node >= N_NODES) return;

  __shared__ int s_src_all[4][64];
  __shared__ float s_alp_all[4][64];
  int* s_src = s_src_all[wv];
  float* s_alp = s_alp_all[wv];

  const int r0 = rowoff[node];
  const int deg = rowoff[node + 1] - r0;
  const float ad = aD[node];

  float acc[4] = {0.f, 0.f, 0.f, 0.f};

  auto gather = [&](int cnt) {
    int e = 0;
    for (; e + 4 <= cnt; e += 4) {
      uint2 v[4];
      float al[4];
#pragma unroll
      for (int u = 0; u < 4; ++u) {
        const int s = s_src[e + u];
        al[u] = s_alp[e + u];
        v[u] = ((const uint2*)(hpre + ((size_t)s << 8)))[lane];
      }
#pragma unroll
      for (int u = 0; u < 4; ++u) {
        float lo, hi;
        up2(v[u].x, lo, hi); acc[0] += al[u] * lo; acc[1] += al[u] * hi;
        up2(v[u].y, lo, hi); acc[2] += al[u] * lo; acc[3] += al[u] * hi;
      }
    }
    for (; e < cnt; ++e) {
      const int s = s_src[e];
      const float al = s_alp[e];
      const uint2 v = ((const uint2*)(hpre + ((size_t)s << 8)))[lane];
      float lo, hi;
      up2(v.x, lo, hi); acc[0] += al * lo; acc[1] += al * hi;
      up2(v.y, lo, hi); acc[2] += al * lo; acc[3] += al * hi;
    }
  };

  if (deg <= 64) {
    float l0;
    int sE = 0;
    const bool act = lane < deg;
    if (act) {
      sE = csr[r0 + lane];
      l0 = lrelu(aS[sE] + ad);
    } else {
      l0 = NEG_INF;
    }
    float m0 = l0;
#pragma unroll
    for (int off = 32; off; off >>= 1) m0 = fmaxf(m0, __shfl_xor(m0, off));
    float e0 = act ? __expf(l0 - m0) : 0.f;
    float s0 = e0;
#pragma unroll
    for (int off = 32; off; off >>= 1) s0 += __shfl_xor(s0, off);
    if (act) {
      s_src[lane] = sE;
      s_alp[lane] = e0 / (s0 + 1e-16f);
    }
    gather(deg);
  } else {
    float m0 = NEG_INF;
    for (int base = 0; base < deg; base += 64)
      if (base + lane < deg) m0 = fmaxf(m0, lrelu(aS[csr[r0 + base + lane]] + ad));
#pragma unroll
    for (int off = 32; off; off >>= 1) m0 = fmaxf(m0, __shfl_xor(m0, off));
    float s0 = 0.f;
    for (int base = 0; base < deg; base += 64)
      if (base + lane < deg) s0 += __expf(lrelu(aS[csr[r0 + base + lane]] + ad) - m0);
#pragma unroll
    for (int off = 32; off; off >>= 1) s0 += __shfl_xor(s0, off);
    const float d0 = 1.f / (s0 + 1e-16f);
    for (int base = 0; base < deg; base += 64) {
      const int cnt = min(64, deg - base);
      if (lane < cnt) {
        const int s = csr[r0 + base + lane];
        s_src[lane] = s;
        s_alp[lane] = __expf(lrelu(aS[s] + ad) - m0) * d0;
      }
      gather(cnt);
    }
  }

  const int c = lane * 4;
  const float4 bi = *(const float4*)&bias[c];
  const float4 gg = *(const float4*)&bn[c];
  const float4 bb = *(const float4*)&bn[256 + c];
  const float4 mm = *(const float4*)&bn[512 + c];
  const float4 vv = *(const float4*)&bn[768 + c];
  float4 o;
#pragma unroll
  for (int j = 0; j < 4; ++j) {
    float v = acc[j] + ((const float*)&bi)[j];
    v = (v - ((const float*)&mm)[j]) *
            (((const float*)&gg)[j] * rsqrtf(((const float*)&vv)[j] + 1e-5f)) +
        ((const float*)&bb)[j];
    v = v > 0.f ? v : (__expf(v) - 1.f);
    ((float*)&o)[j] = v;
  }
  *(float4*)&outf[((size_t)node << 8) + c] = o;
}

// ======================= graph readout =======================
__global__ __launch_bounds__(256) void k_pool(const float* __restrict__ h,
                                              const int* __restrict__ goff,
                                              float* __restrict__ z) {
  const int g = blockIdx.x;
  const int c = threadIdx.x;
  const int i0 = goff[g], i1 = goff[g + 1];
  float s = 0.f, mx = NEG_INF;
  for (int i = i0; i < i1; ++i) {
    float v = h[(size_t)i * 256 + c];
    s += v;
    mx = fmaxf(mx, v);
  }
  const float cnt = (float)(i1 - i0);
  z[(size_t)g * 768 + c] = s / cnt;
  z[(size_t)g * 768 + 256 + c] = mx;
  z[(size_t)g * 768 + 512 + c] = s;
}

// ======================= fc3 =======================
__global__ __launch_bounds__(64) void k_fc3(const float* __restrict__ z2,
                                            const float* __restrict__ w,
                                            const float* __restrict__ b,
                                            float* __restrict__ out) {
  const int g = blockIdx.x;
  const int lane = threadIdx.x;
  float s = 0.f;
#pragma unroll
  for (int j = 0; j < 4; ++j) {
    int c = lane + 64 * j;
    s += z2[(size_t)g * 256 + c] * w[c];
  }
#pragma unroll
  for (int off = 32; off; off >>= 1) s += __shfl_xor(s, off);
  if (lane == 0) out[g] = s + b[0];
}

// ======================= host launch =======================
extern "C" void kernel_launch(void* const* d_in, const int* in_sizes, int n_in,
                              void* d_out, int out_size, void* d_ws, size_t ws_size,
                              hipStream_t stream) {
  const float* x    = (const float*)d_in[0];
  const int* ei     = (const int*)d_in[1];
  const int* batch  = (const int*)d_in[2];
  const float* W1   = (const float*)d_in[3];
  const float* as1  = (const float*)d_in[4];
  const float* ad1  = (const float*)d_in[5];
  const float* b1   = (const float*)d_in[6];
  const float* bn1  = (const float*)d_in[7];
  const float* W2   = (const float*)d_in[8];
  const float* as2  = (const float*)d_in[9];
  const float* ad2  = (const float*)d_in[10];
  const float* b2   = (const float*)d_in[11];
  const float* bn2  = (const float*)d_in[12];
  const float* W3   = (const float*)d_in[13];
  const float* as3  = (const float*)d_in[14];
  const float* ad3  = (const float*)d_in[15];
  const float* b3   = (const float*)d_in[16];
  const float* bn3  = (const float*)d_in[17];
  const float* fc1w = (const float*)d_in[18];
  const float* fc1b = (const float*)d_in[19];
  const float* bnf1 = (const float*)d_in[20];
  const float* fc2w = (const float*)d_in[21];
  const float* fc2b = (const float*)d_in[22];
  const float* bnf2 = (const float*)d_in[23];
  const float* fc3w = (const float*)d_in[24];
  const float* fc3b = (const float*)d_in[25];
  float* out = (float*)d_out;

  const int* e_src = ei;
  const int* e_dst = ei + N_EDGES;

  char* w = (char*)d_ws;
  auto alloc = [&](size_t bytes) -> void* {
    void* p = (void*)w;
    w += (bytes + 255) & ~(size_t)255;
    return p;
  };
  unsigned short* x_bf  = (unsigned short*)alloc((size_t)N_NODES * 128 * 2);
  unsigned short* xt    = (unsigned short*)alloc((size_t)N_NODES * 512 * 2);
  unsigned short* W1t   = (unsigned short*)alloc((size_t)1024 * 128 * 2);
  unsigned short* W2t   = (unsigned short*)alloc((size_t)1024 * 1024 * 2);
  unsigned short* W3t   = (unsigned short*)alloc((size_t)256 * 1024 * 2);
  unsigned short* hA_bf = (unsigned short*)alloc((size_t)N_NODES * 1024 * 2);
  unsigned short* hB_bf = (unsigned short*)alloc((size_t)N_NODES * 1024 * 2);
  float* hB_f32 = (float*)alloc((size_t)N_NODES * 256 * 4);
  float* aS   = (float*)alloc((size_t)N_NODES * 4 * 4);
  float* aD   = (float*)alloc((size_t)N_NODES * 4 * 4);
  float* wS1  = (float*)alloc((size_t)512 * 4);
  float* wD1  = (float*)alloc((size_t)512 * 4);
  int* deg    = (int*)alloc((size_t)(2 * N_NODES + N_GRAPH) * 4);
  int* cursor = deg + N_NODES;
  int* gcnt   = deg + 2 * N_NODES;
  int* rowoff = (int*)alloc((size_t)(N_NODES + 1) * 4);
  int* goff   = (int*)alloc((size_t)(N_GRAPH + 1) * 4);
  int* csr    = (int*)alloc((size_t)N_EDGES * 4);
  float* z    = (float*)alloc((size_t)N_GRAPH * 768 * 4);
  float* z1   = (float*)alloc((size_t)N_GRAPH * 512 * 4);
  float* z2   = (float*)alloc((size_t)N_GRAPH * 256 * 4);

  hipMemsetAsync(deg, 0, (size_t)(2 * N_NODES + N_GRAPH) * 4, stream);

  // conversions + layer-1 attention mix (independent of CSR build)
  k_convT<<<dim3(1024 / 32, 128 / 32), 256, 0, stream>>>(W1, W1t, 128, 1024);
  k_convT<<<dim3(1024 / 32, 1024 / 32), 256, 0, stream>>>(W2, W2t, 1024, 1024);
  k_convT<<<dim3(256 / 32, 1024 / 32), 256, 0, stream>>>(W3, W3t, 1024, 256);
  k_wmix<<<2, 256, 0, stream>>>(W1, as1, ad1, wS1, wD1);
  k_prep_x<<<(N_NODES + 3) / 4, 256, 0, stream>>>(x, wS1, wD1, x_bf, aS, aD);

  // CSR build (by destination) + graph offsets
  k_count<<<(N_EDGES + 255) / 256, 256, 0, stream>>>(e_dst, batch, deg, gcnt);
  k_scan2<<<1, 1024, 0, stream>>>(deg, rowoff, N_NODES, gcnt, goff, N_GRAPH);
  k_fill<<<(N_EDGES + 255) / 256, 256, 0, stream>>>(e_src, e_dst, rowoff, cursor, csr);
  k_sortseg<<<(N_NODES + 3) / 4, 256, 0, stream>>>(rowoff, csr);

  const int mt = (N_NODES + 127) / 128;  // 79
  const int mt8 = 80;                     // pad rows-tiles to multiple of 8 for swizzle
  const int nb2 = (N_NODES + 1) / 2;
  const int nb4 = (N_NODES + 3) / 4;

  // ---- layer 1: aggregate in x-space, then block-diagonal GEMM (fused epi) ----
  k_aggx<<<nb4, 256, 0, stream>>>(x_bf, aS, aD, rowoff, csr, xt);
  k_gemm_l1<<<dim3(8, mt), 256, 0, stream>>>(xt, W1t, hB_bf, N_NODES, b1, bn1);

  // ---- layer 2 ----
  k_gemm_bf16<<<dim3(8, mt8), 256, 0, stream>>>(
      hB_bf, 1024, W2t, 1024, hA_bf, 1024, N_NODES, 1024, 1024, 8);
  k_att<4><<<(N_NODES * 4 + 3) / 4, 256, 0, stream>>>(hA_bf, as2, ad2, aS, aD);
  k_aggw4<<<nb2, 256, 0, stream>>>(hA_bf, aS, aD, rowoff, csr, b2, bn2, hB_bf);

  // ---- layer 3 ----
  k_gemm_bf16<<<dim3(2, mt8), 256, 0, stream>>>(
      hB_bf, 1024, W3t, 1024, hA_bf, 256, N_NODES, 256, 1024, 2);
  k_att<1><<<(N_NODES + 3) / 4, 256, 0, stream>>>(hA_bf, as3, ad3, aS, aD);
  k_aggw1<<<nb4, 256, 0, stream>>>(hA_bf, aS, aD, rowoff, csr, b3, bn3, hB_f32);

  // ---- readout + MLP head ----
  k_pool<<<N_GRAPH, 256, 0, stream>>>(hB_f32, goff, z);
  k_head_fc<768, 512><<<dim3(512 / 64, N_GRAPH / 8), 256, 0, stream>>>(z, fc1w, z1, fc1b, bnf1);
  k_head_fc<512, 256><<<dim3(256 / 64, N_GRAPH / 8), 256, 0, stream>>>(z1, fc2w, z2, fc2b, bnf2);
  k_fc3<<<N_GRAPH, 64, 0, stream>>>(z2, fc3w, fc3b, out);
}